// Round 7
// baseline (11612.106 us; speedup 1.0000x reference)
//
#include <hip/hip_runtime.h>

// Shapes (fixed by the problem)
#define BATCH 256
#define ENCH  512   // encoder hidden (e)
#define WWID  256   // encoder width  (w)
#define ATT   256   // attn size      (a)
#define DECH  256   // decoder hidden (d)
#define EMBD  128
#define VOC   81
#define TT    100

// ---------- numerics: fp32, libm-grade (trajectory must match np fp32 ref) ----
__device__ __forceinline__ float ftanh(float x) {
  float e = expf(2.0f * x);
  return 1.0f - 2.0f / (e + 1.0f);
}
__device__ __forceinline__ float fsig(float x) {
  return 1.0f / (1.0f + expf(-x));
}

// ------------- build transposed weights: W2[k][g], DW2[k][a] -----------------
// W2 rows 0..511 = w_ih ctx part (w_ih[:,128+k]^T), rows 512..767 = w_hh^T.
// Natural gate-major columns g = gate*256 + j.
__global__ void k_build(const float* __restrict__ w_ih, const float* __restrict__ w_hh,
                        const float* __restrict__ dlw,
                        float* __restrict__ W2, float* __restrict__ DW2) {
  int k = blockIdx.x, tid = threadIdx.x;
  if (k < 768) {
    for (int g = tid; g < 1024; g += 256)
      W2[(size_t)k * 1024 + g] = (k < 512) ? w_ih[(size_t)g * 640 + 128 + k]
                                           : w_hh[(size_t)g * 256 + (k - 512)];
  } else {
    int kk = k - 768;
    DW2[kk * 256 + tid] = dlw[tid * 256 + kk];
  }
}

// ---------- emb_gates[v][g] = b_ih[g]+b_hh[g] + sum_e emb[v][e] w_ih[g][e] ---
__global__ void k_embg(const float* __restrict__ emb, const float* __restrict__ w_ih,
                       const float* __restrict__ b_ih, const float* __restrict__ b_hh,
                       float* __restrict__ embg) {
  int v = blockIdx.x, tid = threadIdx.x;
  __shared__ float em[EMBD];
  if (tid < EMBD) em[tid] = emb[v * EMBD + tid];
  __syncthreads();
  for (int g = tid; g < 1024; g += 256) {
    float s = b_ih[g] + b_hh[g];
    const float* wr = w_ih + (size_t)g * 640;
#pragma unroll 8
    for (int e = 0; e < EMBD; ++e) s += em[e] * wr[e];
    embg[v * 1024 + g] = s;
  }
}

// ------------- weighted_enc[b][a][w] = sum_e cw[a][e] enc[b][e][w] + cb[a] ----
__global__ void __launch_bounds__(256) k_we(const float* __restrict__ enc,
                                            const float* __restrict__ cw,
                                            const float* __restrict__ cb,
                                            float* __restrict__ we) {
  int bid = blockIdx.x;
  int b = bid >> 4, at = (bid >> 2) & 3, wt = bid & 3;
  int a0 = at * 64, w0 = wt * 64;
  __shared__ float cwT[32][68];
  __shared__ float encT[32][64];
  int tid = threadIdx.x;
  int tx = tid & 15, ty = tid >> 4;
  float acc[4][4] = {};
  const float* encB = enc + (size_t)b * ENCH * WWID;
  for (int k0 = 0; k0 < ENCH; k0 += 32) {
    {
      int a = tid >> 2, e8 = (tid & 3) * 8;
      const float* src = cw + (size_t)(a0 + a) * ENCH + k0 + e8;
      float4 v0 = *(const float4*)(src);
      float4 v1 = *(const float4*)(src + 4);
      cwT[e8 + 0][a] = v0.x; cwT[e8 + 1][a] = v0.y; cwT[e8 + 2][a] = v0.z; cwT[e8 + 3][a] = v0.w;
      cwT[e8 + 4][a] = v1.x; cwT[e8 + 5][a] = v1.y; cwT[e8 + 6][a] = v1.z; cwT[e8 + 7][a] = v1.w;
    }
    {
      int e = tid >> 3, w8 = (tid & 7) * 8;
      const float* src = encB + (size_t)(k0 + e) * WWID + w0 + w8;
      *(float4*)&encT[e][w8] = *(const float4*)src;
      *(float4*)&encT[e][w8 + 4] = *(const float4*)(src + 4);
    }
    __syncthreads();
#pragma unroll
    for (int e = 0; e < 32; ++e) {
      float4 av = *(const float4*)&cwT[e][ty * 4];
      float4 bv = *(const float4*)&encT[e][tx * 4];
      float a4[4] = {av.x, av.y, av.z, av.w};
      float b4[4] = {bv.x, bv.y, bv.z, bv.w};
#pragma unroll
      for (int i = 0; i < 4; ++i)
#pragma unroll
        for (int j = 0; j < 4; ++j) acc[i][j] += a4[i] * b4[j];
    }
    __syncthreads();
  }
#pragma unroll
  for (int i = 0; i < 4; ++i) {
    int a = a0 + ty * 4 + i;
    float bias = cb[a];
    float4 o;
    o.x = acc[i][0] + bias; o.y = acc[i][1] + bias;
    o.z = acc[i][2] + bias; o.w = acc[i][3] + bias;
    *(float4*)(we + ((size_t)(b * ATT + a)) * WWID + w0 + tx * 4) = o;
  }
}

// =============== persistent 2-batch kernel: all 100 steps ====================
// grid 128 blocks x 1024 threads. Each block owns TWO batches: waves 0-7 run
// batch b0's attention path (exact round-5 8-wave op order), waves 8-15 run
// batch b1's. The gates GEMV is done jointly: one thread per column, each W2
// element loaded ONCE and used for both batches -> W2 L2 stream per batch
// halves. No grid barriers, no atomics.
__global__ void __launch_bounds__(1024, 1) k_loop(
    const float* __restrict__ we, const float* __restrict__ enc,
    const float* __restrict__ W2, const float* __restrict__ DW2,
    const float* __restrict__ embg, const float* __restrict__ dlb,
    const float* __restrict__ ew, const float* __restrict__ eb,
    const float* __restrict__ ow, const float* __restrict__ ob,
    const int* __restrict__ sos, float* __restrict__ out) {
  const int tid = threadIdx.x;
  const int hb = tid >> 9;          // half: 0 -> batch b0, 1 -> batch b1
  const int lt = tid & 511;         // local tid within half (512 threads)
  const int bb = blockIdx.x * 2 + hb;

  __shared__ float xf_s[2][768];    // x = [ctx(0..511) | h(512..767)] per batch
  __shared__ float c_s[2][256];
  __shared__ float dp_s[2][256], sc_s[2][256];
  __shared__ float ew_s[256];
  __shared__ float partA[16][64][4];   // slabs 0-7: b0, 8-15: b1
  __shared__ float gpre_s[2][1024];
  __shared__ float red[2][8];
  __shared__ float lg[2][VOC], lp_s[2][VOC];
  __shared__ int xcur_s[2];

  if (tid < 256) ew_s[tid] = ew[tid];
  if (lt < 256) {
    c_s[hb][lt] = 0.0f;
    xf_s[hb][512 + lt] = 0.0f;      // h(-1) = 0
  }
  if (lt == 0) xcur_s[hb] = sos[0];
  const float ebv = eb[0];
  const float* weB = we + ((size_t)bb << 16);
  const float* encB = enc + (size_t)bb * ENCH * WWID;
  __syncthreads();

  for (int t = 0; t < TT; ++t) {
    // ---------- dp[a] = dlb[a] + sum_k h[k] * DW2[k][a]  (exact r5 order) ----
    if (lt < 256) {
      float acc = dlb[lt];
      const float* dw = DW2 + lt;
      const float* hs = &xf_s[hb][512];
#pragma unroll 8
      for (int k = 0; k < DECH; ++k) acc += dw[k * 256] * hs[k];
      dp_s[hb][lt] = acc;
    }
    __syncthreads();
    // ---------- scores: per half, 8 waves x 32 a-rows (exact r5 order) -------
    {
      int q = lt & 63, pt = lt >> 6;
      float s0 = 0, s1 = 0, s2 = 0, s3 = 0;
      int abase = pt * 32;
#pragma unroll 8
      for (int i = 0; i < 32; ++i) {
        int aa = abase + i;
        float4 wv = *(const float4*)(weB + (size_t)aa * 256 + q * 4);
        float d = dp_s[hb][aa], w8 = ew_s[aa];
        s0 += w8 * ftanh(wv.x + d);
        s1 += w8 * ftanh(wv.y + d);
        s2 += w8 * ftanh(wv.z + d);
        s3 += w8 * ftanh(wv.w + d);
      }
      int slab = hb * 8 + pt;
      partA[slab][q][0] = s0; partA[slab][q][1] = s1;
      partA[slab][q][2] = s2; partA[slab][q][3] = s3;
    }
    __syncthreads();
    // ---------- softmax over w (256), per half (exact r5 order) --------------
    float sv = 0.0f;
    if (lt < 256) {
      sv = ebv;
      const int base = hb * 8;
#pragma unroll
      for (int p = 0; p < 8; ++p) sv += partA[base + p][lt >> 2][lt & 3];
      float mm = sv;
      for (int off = 32; off; off >>= 1) mm = fmaxf(mm, __shfl_xor(mm, off));
      if ((lt & 63) == 0) red[hb][lt >> 6] = mm;
    }
    __syncthreads();
    float mA = fmaxf(fmaxf(red[hb][0], red[hb][1]), fmaxf(red[hb][2], red[hb][3]));
    float pa = 0.0f;
    if (lt < 256) {
      pa = expf(sv - mA);
      float ss = pa;
      for (int off = 32; off; off >>= 1) ss += __shfl_xor(ss, off);
      if ((lt & 63) == 0) red[hb][4 + (lt >> 6)] = ss;
    }
    __syncthreads();
    {
      float S = red[hb][4] + red[hb][5] + red[hb][6] + red[hb][7];
      if (lt < 256) {
        float alpha = pa / S;
        sc_s[hb][lt] = alpha;
        out[(size_t)(BATCH * TT * VOC) + (size_t)(BATCH * TT) +
            ((size_t)bb * TT + t) * WWID + lt] = alpha;
      }
    }
    __syncthreads();
    // ---------- context[e] = sum_w enc[b][e][w]*alpha[w] (exact r5 order) ----
    {
      int lane = lt & 63, wvi = lt >> 6;
      float4 al = *(const float4*)&sc_s[hb][lane * 4];
#pragma unroll 2
      for (int e = wvi; e < ENCH; e += 8) {
        float4 evv = *(const float4*)(encB + (size_t)e * WWID + lane * 4);
        float s = evv.x * al.x + evv.y * al.y + evv.z * al.z + evv.w * al.w;
        for (int off = 32; off; off >>= 1) s += __shfl_xor(s, off);
        if (lane == 0) xf_s[hb][e] = s;
      }
    }
    __syncthreads();
    // ---------- gates GEMV: joint over both batches; W2 loaded once ----------
    // one thread per column g=tid; per-column K-order identical to round 6
    {
      float a0 = 0.0f, a1 = 0.0f;
      const float* w0 = W2 + tid;
#pragma unroll 2
      for (int k4 = 0; k4 < 192; ++k4) {
        float4 x0 = *(const float4*)&xf_s[0][k4 * 4];
        float4 x1 = *(const float4*)&xf_s[1][k4 * 4];
        const float* wp = w0 + (size_t)k4 * 4096;
        float w_0 = wp[0], w_1 = wp[1024], w_2 = wp[2048], w_3 = wp[3072];
        a0 += w_0 * x0.x + w_1 * x0.y + w_2 * x0.z + w_3 * x0.w;
        a1 += w_0 * x1.x + w_1 * x1.y + w_2 * x1.z + w_3 * x1.w;
      }
      gpre_s[0][tid] = a0 + embg[(size_t)xcur_s[0] * 1024 + tid];
      gpre_s[1][tid] = a1 + embg[(size_t)xcur_s[1] * 1024 + tid];
    }
    __syncthreads();
    // ---------- LSTM cell, per half (exact r5 values) ------------------------
    if (lt < 256) {
      float iv = fsig(gpre_s[hb][lt]);
      float fv = fsig(gpre_s[hb][256 + lt]);
      float gv = ftanh(gpre_s[hb][512 + lt]);
      float ov = fsig(gpre_s[hb][768 + lt]);
      float cn = fv * c_s[hb][lt] + iv * gv;
      float hn = ov * ftanh(cn);
      c_s[hb][lt] = cn;
      xf_s[hb][512 + lt] = hn;      // h(t)
    }
    __syncthreads();
    // ---------- logits + log_softmax + argmax, per half (exact r5 order) -----
    {
      int lane = lt & 63, wv = lt >> 6;
      float4 hh = *(const float4*)&xf_s[hb][512 + lane * 4];
      for (int v = wv; v < VOC; v += 8) {
        float4 wr = *(const float4*)(ow + (size_t)v * 256 + lane * 4);
        float s = wr.x * hh.x + wr.y * hh.y + wr.z * hh.z + wr.w * hh.w;
        for (int off = 32; off; off >>= 1) s += __shfl_xor(s, off);
        if (lane == 0) lg[hb][v] = s + ob[v];
      }
    }
    __syncthreads();
    float v_ = -3.402823e38f, pe = 0.0f;
    if (lt < 256) {
      v_ = (lt < VOC) ? lg[hb][lt] : -3.402823e38f;
      float mm = v_;
      for (int off = 32; off; off >>= 1) mm = fmaxf(mm, __shfl_xor(mm, off));
      if ((lt & 63) == 0) red[hb][lt >> 6] = mm;
    }
    __syncthreads();
    float mC = fmaxf(fmaxf(red[hb][0], red[hb][1]), fmaxf(red[hb][2], red[hb][3]));
    if (lt < 256) {
      pe = (lt < VOC) ? expf(v_ - mC) : 0.0f;
      float ss = pe;
      for (int off = 32; off; off >>= 1) ss += __shfl_xor(ss, off);
      if ((lt & 63) == 0) red[hb][4 + (lt >> 6)] = ss;
    }
    __syncthreads();
    {
      float S = red[hb][4] + red[hb][5] + red[hb][6] + red[hb][7];
      float lse = mC + logf(S);
      if (lt < VOC) {
        float lp = v_ - lse;
        lp_s[hb][lt] = lp;
        out[((size_t)bb * TT + t) * VOC + lt] = lp;
      }
    }
    __syncthreads();
    if (lt == 0) {
      int best = 0;
      float bv = lp_s[hb][0];
      for (int v = 1; v < VOC; ++v) {
        float x = lp_s[hb][v];
        if (x > bv) { bv = x; best = v; }
      }
      xcur_s[hb] = best;
      out[(size_t)(BATCH * TT * VOC) + (size_t)bb * TT + t] = (float)best;
    }
    __syncthreads();
  }
}

extern "C" void kernel_launch(void* const* d_in, const int* in_sizes, int n_in,
                              void* d_out, int out_size, void* d_ws, size_t ws_size,
                              hipStream_t stream) {
  (void)in_sizes; (void)n_in; (void)out_size; (void)ws_size;
  const float* enc = (const float*)d_in[0];
  const float* emb = (const float*)d_in[1];
  const float* ecw = (const float*)d_in[2];
  const float* ecb = (const float*)d_in[3];
  const float* dlw = (const float*)d_in[4];
  const float* dlb = (const float*)d_in[5];
  const float* ew  = (const float*)d_in[6];
  const float* eb  = (const float*)d_in[7];
  const float* wih = (const float*)d_in[8];
  const float* whh = (const float*)d_in[9];
  const float* bih = (const float*)d_in[10];
  const float* bhh = (const float*)d_in[11];
  const float* ow  = (const float*)d_in[12];
  const float* ob  = (const float*)d_in[13];
  const int* sos   = (const int*)d_in[15];
  float* out = (float*)d_out;
  float* ws = (float*)d_ws;

  // workspace map (floats); ~17.7M floats ~ 71 MB
  size_t off = 0;
  float* we    = ws + off; off += (size_t)BATCH * ATT * WWID;  // 16,777,216
  float* W2    = ws + off; off += (size_t)768 * 1024;
  float* DW2   = ws + off; off += (size_t)256 * 256;
  float* embg  = ws + off; off += (size_t)VOC * 1024;

  k_build<<<1024, 256, 0, stream>>>(wih, whh, dlw, W2, DW2);
  k_embg<<<VOC, 256, 0, stream>>>(emb, wih, bih, bhh, embg);
  k_we<<<4096, 256, 0, stream>>>(enc, ecw, ecb, we);
  k_loop<<<128, 1024, 0, stream>>>(we, enc, W2, DW2, embg, dlb, ew, eb, ow, ob,
                                   sos, out);
}